// Round 7
// baseline (214.202 us; speedup 1.0000x reference)
//
#include <hip/hip_runtime.h>
#include <hip/hip_bf16.h>

// DARTS MixedOp. B=64, C=128, H=W=32. Per-sample top-k(2) masked-softmax gate
// over 8 ops. Inputs fp32 (R3/R4 A/B-confirmed), outputs fp32.
//
// R7: fat pw threads (8co x 4hw: 32 FMA per dwordx2 load), W pre-scaled by
// gate*BN into padded LDS (broadcast reads, no per-ci scalar loads, direct
// multi-instance accumulation), bf16 pool tile (18KB LDS), finer grids.
//
// ws: gates[64*8]f32 @0 | cnum[64] @2048 | cops[64*4] @2304 | 8 bf16 bufs
// of 16.8MB @4096 (A4 A5 B4 B5 P4 P5 P6 P7) = ~134MB.

#define BN_SCALE 0.9999950000374997f  // 1/sqrt(1+1e-5)
#define BB 64
#define CC 128
#define HH 32
#define WW 32
#define PLANE (HH*WW)          // 1024
#define SAMP (CC*PLANE)        // 131072
#define NOUT0 (BB*SAMP)        // 8388608

__device__ __forceinline__ float us2f(unsigned int u) {
    unsigned int x = (u & 0xffffu) << 16;
    float f; __builtin_memcpy(&f, &x, 4); return f;
}
__device__ __forceinline__ unsigned short f2us(float f) {
    __hip_bfloat16 h = __float2bfloat16(f);
    unsigned short u; __builtin_memcpy(&u, &h, 2); return u;
}

// ---------------------------------------------------------------- gates
__global__ void k_gates(const float* __restrict__ wlog,
                        const void* __restrict__ topp,
                        float* __restrict__ gates,
                        int* __restrict__ cnum, int* __restrict__ cops,
                        float* __restrict__ out_w) {
    int b = threadIdx.x;                    // block is exactly 64 threads

    // robust `top` parse: int32 / int64-low / fp32 / bf16
    int top = -1;
    {
        unsigned int u0 = *(const unsigned int*)topp;
        int i32 = (int)u0;
        if (i32 >= 1 && i32 <= 8) top = i32;
        else {
            float f32; __builtin_memcpy(&f32, &u0, 4);
            if (f32 >= 1.f && f32 <= 8.f) top = (int)(f32 + 0.5f);
            else { float fb = us2f(u0); if (fb >= 1.f && fb <= 8.f) top = (int)(fb + 0.5f); }
        }
        if (top < 1 || top > 8) top = 2;
    }

    float lw[8];
    #pragma unroll
    for (int i = 0; i < 8; ++i) {
        lw[i] = wlog[b * 8 + i];
        out_w[b * 8 + i] = lw[i];           // output 1: clone of logits
    }
    bool sel[8] = {false,false,false,false,false,false,false,false};
    for (int t = 0; t < top; ++t) {         // lax.top_k tie-break: lowest index
        int best = -1; float bv = -3.4e38f;
        #pragma unroll
        for (int i = 0; i < 8; ++i)
            if (!sel[i] && lw[i] > bv) { bv = lw[i]; best = i; }
        if (best >= 0) sel[best] = true;
    }
    float m = -3.4e38f;
    #pragma unroll
    for (int i = 0; i < 8; ++i) if (sel[i] && lw[i] > m) m = lw[i];
    float s = 0.f, e[8];
    #pragma unroll
    for (int i = 0; i < 8; ++i) { e[i] = sel[i] ? expf(lw[i] - m) : 0.f; s += e[i]; }
    float inv = (s > 0.f) ? 1.f / s : 0.f;
    float g[8];
    #pragma unroll
    for (int i = 0; i < 8; ++i) {
        g[i] = (s > 0.f) ? e[i] * inv : (sel[i] ? 1.f / (float)top : 0.f);
        gates[b * 8 + i] = g[i];
    }
    int n = 0;
    #pragma unroll
    for (int i = 4; i < 8; ++i)
        if (g[i] > 0.f) { if (n < 4) cops[b * 4 + n] = i; ++n; }
    cnum[b] = (n < 4) ? n : 4;
}

// ------------------------------------------- depthwise conv helper
template <int K, int DIL>
__device__ __forceinline__ void dw_comp(const float* __restrict__ sx,
                                        const float* __restrict__ wd, int c,
                                        unsigned short* __restrict__ opp) {
    constexpr int PAD = (K / 2) * DIL;
    float wk[K * K];
    #pragma unroll
    for (int i = 0; i < K * K; ++i) wk[i] = wd[c * K * K + i];
    #pragma unroll
    for (int j = 0; j < 4; ++j) {
        int px = threadIdx.x + j * 256;
        int h = px >> 5, w = px & 31;
        float acc = 0.f;
        #pragma unroll
        for (int ky = 0; ky < K; ++ky) {
            int ih = h + ky * DIL - PAD;
            if ((unsigned)ih >= HH) continue;
            #pragma unroll
            for (int kx = 0; kx < K; ++kx) {
                int iw = w + kx * DIL - PAD;
                if ((unsigned)iw >= WW) continue;
                acc = fmaf(wk[ky * K + kx], sx[ih * WW + iw], acc);
            }
        }
        opp[px] = f2us(acc);
    }
}

// ---------------------------------- first dw for all 4 conv ops (from x)
__global__ __launch_bounds__(256) void
k_dw_first(const float* __restrict__ x,
           const float* __restrict__ w4, const float* __restrict__ w5,
           const float* __restrict__ w6, const float* __restrict__ w7,
           const float* __restrict__ gates,
           unsigned short* __restrict__ A4, unsigned short* __restrict__ A5,
           unsigned short* __restrict__ P6, unsigned short* __restrict__ P7) {
    int plane = blockIdx.x;            // b*128 + c
    int b = plane >> 7, c = plane & 127;
    float g4 = gates[b * 8 + 4], g5 = gates[b * 8 + 5];
    float g6 = gates[b * 8 + 6], g7 = gates[b * 8 + 7];
    if (g4 == 0.f && g5 == 0.f && g6 == 0.f && g7 == 0.f) return;
    __shared__ float sx[PLANE];
    {
        float4 v = ((const float4*)(x + (size_t)plane * PLANE))[threadIdx.x];
        ((float4*)sx)[threadIdx.x] =
            make_float4(fmaxf(v.x, 0.f), fmaxf(v.y, 0.f),
                        fmaxf(v.z, 0.f), fmaxf(v.w, 0.f));
    }
    __syncthreads();
    size_t off = (size_t)plane * PLANE;
    if (g4 != 0.f) dw_comp<3, 1>(sx, w4, c, A4 + off);
    if (g5 != 0.f) dw_comp<5, 1>(sx, w5, c, A5 + off);
    if (g6 != 0.f) dw_comp<3, 2>(sx, w6, c, P6 + off);
    if (g7 != 0.f) dw_comp<5, 2>(sx, w7, c, P7 + off);
}

// ---------------------------------- second dw for sep ops (from bufB)
__global__ __launch_bounds__(256) void
k_dw_second(const unsigned short* __restrict__ B4,
            const unsigned short* __restrict__ B5,
            const float* __restrict__ w4, const float* __restrict__ w5,
            const float* __restrict__ gates,
            unsigned short* __restrict__ P4, unsigned short* __restrict__ P5) {
    int plane = blockIdx.x;            // b*128 + c
    int b = plane >> 7, c = plane & 127;
    float g4 = gates[b * 8 + 4], g5 = gates[b * 8 + 5];
    if (g4 == 0.f && g5 == 0.f) return;
    __shared__ float sx[PLANE];
    size_t off = (size_t)plane * PLANE;
    if (g4 != 0.f) {                       // block-uniform branch
        ushort4 v = ((const ushort4*)(B4 + off))[threadIdx.x];
        ((float4*)sx)[threadIdx.x] =
            make_float4(fmaxf(us2f(v.x), 0.f), fmaxf(us2f(v.y), 0.f),
                        fmaxf(us2f(v.z), 0.f), fmaxf(us2f(v.w), 0.f));
        __syncthreads();
        dw_comp<3, 1>(sx, w4, c, P4 + off);
        __syncthreads();
    }
    if (g5 != 0.f) {
        ushort4 v = ((const ushort4*)(B5 + off))[threadIdx.x];
        ((float4*)sx)[threadIdx.x] =
            make_float4(fmaxf(us2f(v.x), 0.f), fmaxf(us2f(v.y), 0.f),
                        fmaxf(us2f(v.z), 0.f), fmaxf(us2f(v.w), 0.f));
        __syncthreads();
        dw_comp<5, 1>(sx, w5, c, P5 + off);
    }
}

// ---------------- pw building blocks (fat threads: 8 co x 4 hw each) ----
#define WLROW 17   // padded LDS row (floats): staging writes 2-way = free

__device__ __forceinline__ void stage_w(float* __restrict__ Wl,
                                        const float* __restrict__ W,
                                        int co0, float s) {
    #pragma unroll
    for (int i = 0; i < 8; ++i) {
        int idx = threadIdx.x + i * 256;        // 2048 = 16 co x 128 ci
        int c = idx >> 7, ci = idx & 127;
        Wl[ci * WLROW + c] = W[(co0 + c) * CC + ci] * s;
    }
}

__device__ __forceinline__ void pw_fat(const unsigned short* __restrict__ ib,
                                       const float* __restrict__ Wl,
                                       int cg, int hw, float acc[8][4]) {
    const float* wr0 = Wl + cg * 8;
    for (int ci = 0; ci < CC; ++ci) {
        uint2 raw = *reinterpret_cast<const uint2*>(ib + ci * PLANE + hw);
        float v0 = us2f(raw.x), v1 = us2f(raw.x >> 16);
        float v2 = us2f(raw.y), v3 = us2f(raw.y >> 16);
        const float* wr = wr0 + ci * WLROW;     // wave-uniform -> broadcast
        #pragma unroll
        for (int k = 0; k < 8; ++k) {
            float wv = wr[k];
            acc[k][0] = fmaf(wv, v0, acc[k][0]);
            acc[k][1] = fmaf(wv, v1, acc[k][1]);
            acc[k][2] = fmaf(wv, v2, acc[k][2]);
            acc[k][3] = fmaf(wv, v3, acc[k][3]);
        }
    }
}

// ---------------------------------- mid pw for sep ops 4,5 (A -> B, *BN)
__global__ __launch_bounds__(256) void
k_pw_mid(const unsigned short* __restrict__ A4,
         const unsigned short* __restrict__ A5,
         const float* __restrict__ W4, const float* __restrict__ W5,
         const float* __restrict__ gates,
         unsigned short* __restrict__ B4, unsigned short* __restrict__ B5) {
    int blk = blockIdx.x;              // b*32 + opi*16 + cog*2 + hws
    int tile = blk & 15;
    int opi  = (blk >> 4) & 1;
    int b    = blk >> 5;
    if (gates[b * 8 + 4 + opi] == 0.f) return;
    int cog = tile >> 1, hws = tile & 1;
    int co0 = cog * 16;
    int cg = threadIdx.x >> 7, ht = threadIdx.x & 127;
    int hw = hws * 512 + ht * 4;
    __shared__ float Wl[128 * WLROW];
    stage_w(Wl, opi ? W5 : W4, co0, BN_SCALE);
    __syncthreads();
    const unsigned short* ib = (opi ? A5 : A4) + (size_t)b * SAMP;
    float acc[8][4] = {};
    pw_fat(ib, Wl, cg, hw, acc);
    unsigned short* ob = opi ? B5 : B4;
    #pragma unroll
    for (int k = 0; k < 8; ++k) {
        size_t idx = (size_t)(b * CC + co0 + cg * 8 + k) * PLANE + hw;
        uint2 pk;
        pk.x = (unsigned int)f2us(acc[k][0]) | ((unsigned int)f2us(acc[k][1]) << 16);
        pk.y = (unsigned int)f2us(acc[k][2]) | ((unsigned int)f2us(acc[k][3]) << 16);
        *reinterpret_cast<uint2*>(ob + idx) = pk;
    }
}

// ------------- final: pools + skip + gated final pw, single out write
__global__ __launch_bounds__(256) void
k_pw_final(const float* __restrict__ x,
           const unsigned short* __restrict__ P4,
           const unsigned short* __restrict__ P5,
           const unsigned short* __restrict__ P6,
           const unsigned short* __restrict__ P7,
           const float* __restrict__ W4, const float* __restrict__ W5,
           const float* __restrict__ W6, const float* __restrict__ W7,
           const float* __restrict__ gates,
           const int* __restrict__ cnum, const int* __restrict__ cops,
           float* __restrict__ out) {
    int blk = blockIdx.x;              // b*16 + cog*2 + hws
    int tile = blk & 15;
    int b    = blk >> 4;
    int cog = tile >> 1, hws = tile & 1;
    int co0 = cog * 16;
    int cg = threadIdx.x >> 7, ht = threadIdx.x & 127;
    int hw = hws * 512 + ht * 4;

    float g1 = gates[b * 8 + 1] * BN_SCALE;   // max_pool -> BN
    float g2 = gates[b * 8 + 2] * BN_SCALE;   // avg_pool -> BN
    float g3 = gates[b * 8 + 3];              // skip
    bool haspool = (g1 != 0.f) | (g2 != 0.f) | (g3 != 0.f);

    __shared__ float Wl[128 * WLROW];          // 8.7 KB
    __shared__ unsigned short sxp[16 * 18 * 32]; // 18 KB bf16 pool tile

    int r0 = hws * 16;
    if (haspool) {                            // block-uniform
        for (int li = threadIdx.x; li < 16 * 18 * 8; li += 256) {
            int ch = li / 144, rem = li - ch * 144;
            int row = rem >> 3, c4 = rem & 7;
            int gr = r0 + row - 1;
            if ((unsigned)gr < HH) {
                float4 v = *(const float4*)(x + ((size_t)(b * CC + co0 + ch) * HH + gr) * WW + c4 * 4);
                ushort4 pv;
                pv.x = f2us(v.x); pv.y = f2us(v.y); pv.z = f2us(v.z); pv.w = f2us(v.w);
                *(ushort4*)(sxp + (ch * 18 + row) * 32 + c4 * 4) = pv;
            }
        }
    }
    __syncthreads();

    // gated final pointwise convs: gate*BN folded into staged W -> direct acc
    float acc[8][4] = {};
    int n = cnum[b];
    for (int t = 0; t < n; ++t) {
        int op = cops[b * 4 + t];
        float gs = gates[b * 8 + op] * BN_SCALE;
        const unsigned short* src;
        const float* W;
        switch (op) {
            case 4:  src = P4; W = W4; break;
            case 5:  src = P5; W = W5; break;
            case 6:  src = P6; W = W6; break;
            default: src = P7; W = W7; break;
        }
        __syncthreads();                      // prior Wl reads done
        stage_w(Wl, W, co0, gs);
        __syncthreads();
        pw_fat(src + (size_t)b * SAMP, Wl, cg, hw, acc);
    }

    // pools + skip term, then single store
    int h = hw >> 5, w = hw & 31;
    int lr = h - r0 + 1;
    #pragma unroll
    for (int k = 0; k < 8; ++k) {
        if (haspool) {
            const unsigned short* sp = sxp + (cg * 8 + k) * 18 * 32;
            #pragma unroll
            for (int jj = 0; jj < 4; ++jj) {
                int ww = w + jj;
                float mx = -3.4e38f, sm = 0.f;
                int cnt = 0;
                #pragma unroll
                for (int dh = -1; dh <= 1; ++dh) {
                    int ih = h + dh;
                    if ((unsigned)ih >= HH) continue;
                    #pragma unroll
                    for (int dw = -1; dw <= 1; ++dw) {
                        int iw = ww + dw;
                        if ((unsigned)iw >= WW) continue;
                        float v = us2f(sp[(lr + dh) * 32 + iw]);
                        mx = fmaxf(mx, v);
                        sm += v;
                        ++cnt;
                    }
                }
                acc[k][jj] += g1 * mx + g2 * (sm / (float)cnt)
                            + g3 * us2f(sp[lr * 32 + ww]);
            }
        }
        *(float4*)(out + (size_t)(b * CC + co0 + cg * 8 + k) * PLANE + hw) =
            make_float4(acc[k][0], acc[k][1], acc[k][2], acc[k][3]);
    }
}

// ---------------------------------------------------------------- launch
extern "C" void kernel_launch(void* const* d_in, const int* in_sizes, int n_in,
                              void* d_out, int out_size, void* d_ws, size_t ws_size,
                              hipStream_t stream) {
    const float* x      = (const float*)d_in[0];
    const float* wlog   = (const float*)d_in[1];
    const float* sc3_d1 = (const float*)d_in[2];
    const float* sc3_p1 = (const float*)d_in[3];
    const float* sc3_d2 = (const float*)d_in[4];
    const float* sc3_p2 = (const float*)d_in[5];
    const float* sc5_d1 = (const float*)d_in[6];
    const float* sc5_p1 = (const float*)d_in[7];
    const float* sc5_d2 = (const float*)d_in[8];
    const float* sc5_p2 = (const float*)d_in[9];
    const float* dc3_d  = (const float*)d_in[10];
    const float* dc3_p  = (const float*)d_in[11];
    const float* dc5_d  = (const float*)d_in[12];
    const float* dc5_p  = (const float*)d_in[13];
    const void* topp    = d_in[14];

    float* out  = (float*)d_out;
    float* outw = out + NOUT0;

    float* gates = (float*)d_ws;
    int*   cnum  = (int*)((char*)d_ws + 2048);
    int*   cops  = (int*)((char*)d_ws + 2304);
    unsigned short* base = (unsigned short*)((char*)d_ws + 4096);
    unsigned short* A4 = base;
    unsigned short* A5 = base + (size_t)NOUT0;
    unsigned short* B4 = base + (size_t)NOUT0 * 2;
    unsigned short* B5 = base + (size_t)NOUT0 * 3;
    unsigned short* P4 = base + (size_t)NOUT0 * 4;
    unsigned short* P5 = base + (size_t)NOUT0 * 5;
    unsigned short* P6 = base + (size_t)NOUT0 * 6;
    unsigned short* P7 = base + (size_t)NOUT0 * 7;

    k_gates<<<1, 64, 0, stream>>>(wlog, topp, gates, cnum, cops, outw);
    k_dw_first<<<BB * CC, 256, 0, stream>>>(x, sc3_d1, sc5_d1, dc3_d, dc5_d,
                                            gates, A4, A5, P6, P7);
    k_pw_mid<<<BB * 32, 256, 0, stream>>>(A4, A5, sc3_p1, sc5_p1, gates, B4, B5);
    k_dw_second<<<BB * CC, 256, 0, stream>>>(B4, B5, sc3_d2, sc5_d2, gates, P4, P5);
    k_pw_final<<<BB * 16, 256, 0, stream>>>(x, P4, P5, P6, P7,
                                            sc3_p2, sc5_p2, dc3_p, dc5_p,
                                            gates, cnum, cops, out);
}

// Round 8
// 196.911 us; speedup vs baseline: 1.0878x; 1.0878x over previous
//
#include <hip/hip_runtime.h>
#include <hip/hip_bf16.h>

// DARTS MixedOp. B=64, C=128, H=W=32. Per-sample top-k(2) masked-softmax gate
// over 8 ops. Inputs fp32 (R3/R4 A/B-confirmed), outputs fp32.
//
// R8: pointwise 1x1 convs moved to MFMA bf16 (16x16x32): W (gate*BN folded)
// and transposed In tiles staged in LDS (136-ushort padded rows), frags via
// ds_read_b128. Pools/skip/init back to standalone k_pools (R5, proven);
// final MFMA kernel RMW-accumulates conv instances into out. dw unchanged.
//
// ws: gates[64*8]f32 @0 | cnum[64] @2048 | cops[64*4] @2304 | 8 bf16 bufs
// of 16.8MB @4096 (A4 A5 B4 B5 P4 P5 P6 P7) = ~134MB.

#define BN_SCALE 0.9999950000374997f  // 1/sqrt(1+1e-5)
#define BB 64
#define CC 128
#define HH 32
#define WW 32
#define PLANE (HH*WW)          // 1024
#define SAMP (CC*PLANE)        // 131072
#define NOUT0 (BB*SAMP)        // 8388608
#define LROW 136               // padded LDS row in ushorts (128 + 8)

typedef __attribute__((ext_vector_type(8))) short bf16x8;
typedef __attribute__((ext_vector_type(4))) float f32x4;

__device__ __forceinline__ float us2f(unsigned int u) {
    unsigned int x = (u & 0xffffu) << 16;
    float f; __builtin_memcpy(&f, &x, 4); return f;
}
__device__ __forceinline__ unsigned short f2us(float f) {
    __hip_bfloat16 h = __float2bfloat16(f);
    unsigned short u; __builtin_memcpy(&u, &h, 2); return u;
}

// ---------------------------------------------------------------- gates
__global__ void k_gates(const float* __restrict__ wlog,
                        const void* __restrict__ topp,
                        float* __restrict__ gates,
                        int* __restrict__ cnum, int* __restrict__ cops,
                        float* __restrict__ out_w) {
    int b = threadIdx.x;                    // block is exactly 64 threads

    int top = -1;                           // robust `top` parse
    {
        unsigned int u0 = *(const unsigned int*)topp;
        int i32 = (int)u0;
        if (i32 >= 1 && i32 <= 8) top = i32;
        else {
            float f32; __builtin_memcpy(&f32, &u0, 4);
            if (f32 >= 1.f && f32 <= 8.f) top = (int)(f32 + 0.5f);
            else { float fb = us2f(u0); if (fb >= 1.f && fb <= 8.f) top = (int)(fb + 0.5f); }
        }
        if (top < 1 || top > 8) top = 2;
    }

    float lw[8];
    #pragma unroll
    for (int i = 0; i < 8; ++i) {
        lw[i] = wlog[b * 8 + i];
        out_w[b * 8 + i] = lw[i];           // output 1: clone of logits
    }
    bool sel[8] = {false,false,false,false,false,false,false,false};
    for (int t = 0; t < top; ++t) {         // lax.top_k tie-break: lowest index
        int best = -1; float bv = -3.4e38f;
        #pragma unroll
        for (int i = 0; i < 8; ++i)
            if (!sel[i] && lw[i] > bv) { bv = lw[i]; best = i; }
        if (best >= 0) sel[best] = true;
    }
    float m = -3.4e38f;
    #pragma unroll
    for (int i = 0; i < 8; ++i) if (sel[i] && lw[i] > m) m = lw[i];
    float s = 0.f, e[8];
    #pragma unroll
    for (int i = 0; i < 8; ++i) { e[i] = sel[i] ? expf(lw[i] - m) : 0.f; s += e[i]; }
    float inv = (s > 0.f) ? 1.f / s : 0.f;
    float g[8];
    #pragma unroll
    for (int i = 0; i < 8; ++i) {
        g[i] = (s > 0.f) ? e[i] * inv : (sel[i] ? 1.f / (float)top : 0.f);
        gates[b * 8 + i] = g[i];
    }
    int n = 0;
    #pragma unroll
    for (int i = 4; i < 8; ++i)
        if (g[i] > 0.f) { if (n < 4) cops[b * 4 + n] = i; ++n; }
    cnum[b] = (n < 4) ? n : 4;
}

// ------------------------------- pools + skip + out init (R5, proven)
__global__ __launch_bounds__(256) void
k_pools(const float* __restrict__ x,
        const float* __restrict__ gates,
        float* __restrict__ out) {
    int plane = blockIdx.x;            // b*128 + c
    int b = plane >> 7;
    float g1 = gates[b * 8 + 1] * BN_SCALE;
    float g2 = gates[b * 8 + 2] * BN_SCALE;
    float g3 = gates[b * 8 + 3];
    float* op = out + (size_t)plane * PLANE;
    if (g1 == 0.f && g2 == 0.f && g3 == 0.f) {
        ((float4*)op)[threadIdx.x] = make_float4(0.f, 0.f, 0.f, 0.f);
        return;
    }
    __shared__ float sx[PLANE];
    ((float4*)sx)[threadIdx.x] = ((const float4*)(x + (size_t)plane * PLANE))[threadIdx.x];
    __syncthreads();
    #pragma unroll
    for (int j = 0; j < 4; ++j) {
        int px = threadIdx.x + j * 256;
        int h = px >> 5, w = px & 31;
        float mx = -3.4e38f, sm = 0.f;
        int cnt = 0;
        #pragma unroll
        for (int dh = -1; dh <= 1; ++dh) {
            int ih = h + dh;
            if ((unsigned)ih >= HH) continue;
            #pragma unroll
            for (int dw = -1; dw <= 1; ++dw) {
                int iw = w + dw;
                if ((unsigned)iw >= WW) continue;
                float v = sx[ih * WW + iw];
                mx = fmaxf(mx, v);
                sm += v;
                ++cnt;
            }
        }
        op[px] = g1 * mx + g2 * (sm / (float)cnt) + g3 * sx[px];
    }
}

// ------------------------------------------- depthwise conv helper
template <int K, int DIL>
__device__ __forceinline__ void dw_comp(const float* __restrict__ sx,
                                        const float* __restrict__ wd, int c,
                                        unsigned short* __restrict__ opp) {
    constexpr int PAD = (K / 2) * DIL;
    float wk[K * K];
    #pragma unroll
    for (int i = 0; i < K * K; ++i) wk[i] = wd[c * K * K + i];
    #pragma unroll
    for (int j = 0; j < 4; ++j) {
        int px = threadIdx.x + j * 256;
        int h = px >> 5, w = px & 31;
        float acc = 0.f;
        #pragma unroll
        for (int ky = 0; ky < K; ++ky) {
            int ih = h + ky * DIL - PAD;
            if ((unsigned)ih >= HH) continue;
            #pragma unroll
            for (int kx = 0; kx < K; ++kx) {
                int iw = w + kx * DIL - PAD;
                if ((unsigned)iw >= WW) continue;
                acc = fmaf(wk[ky * K + kx], sx[ih * WW + iw], acc);
            }
        }
        opp[px] = f2us(acc);
    }
}

// ---------------------------------- first dw for all 4 conv ops (from x)
__global__ __launch_bounds__(256) void
k_dw_first(const float* __restrict__ x,
           const float* __restrict__ w4, const float* __restrict__ w5,
           const float* __restrict__ w6, const float* __restrict__ w7,
           const float* __restrict__ gates,
           unsigned short* __restrict__ A4, unsigned short* __restrict__ A5,
           unsigned short* __restrict__ P6, unsigned short* __restrict__ P7) {
    int plane = blockIdx.x;            // b*128 + c
    int b = plane >> 7, c = plane & 127;
    float g4 = gates[b * 8 + 4], g5 = gates[b * 8 + 5];
    float g6 = gates[b * 8 + 6], g7 = gates[b * 8 + 7];
    if (g4 == 0.f && g5 == 0.f && g6 == 0.f && g7 == 0.f) return;
    __shared__ float sx[PLANE];
    {
        float4 v = ((const float4*)(x + (size_t)plane * PLANE))[threadIdx.x];
        ((float4*)sx)[threadIdx.x] =
            make_float4(fmaxf(v.x, 0.f), fmaxf(v.y, 0.f),
                        fmaxf(v.z, 0.f), fmaxf(v.w, 0.f));
    }
    __syncthreads();
    size_t off = (size_t)plane * PLANE;
    if (g4 != 0.f) dw_comp<3, 1>(sx, w4, c, A4 + off);
    if (g5 != 0.f) dw_comp<5, 1>(sx, w5, c, A5 + off);
    if (g6 != 0.f) dw_comp<3, 2>(sx, w6, c, P6 + off);
    if (g7 != 0.f) dw_comp<5, 2>(sx, w7, c, P7 + off);
}

// ---------------------------------- second dw for sep ops (from bufB)
__global__ __launch_bounds__(256) void
k_dw_second(const unsigned short* __restrict__ B4,
            const unsigned short* __restrict__ B5,
            const float* __restrict__ w4, const float* __restrict__ w5,
            const float* __restrict__ gates,
            unsigned short* __restrict__ P4, unsigned short* __restrict__ P5) {
    int plane = blockIdx.x;            // b*128 + c
    int b = plane >> 7, c = plane & 127;
    float g4 = gates[b * 8 + 4], g5 = gates[b * 8 + 5];
    if (g4 == 0.f && g5 == 0.f) return;
    __shared__ float sx[PLANE];
    size_t off = (size_t)plane * PLANE;
    if (g4 != 0.f) {                       // block-uniform branch
        ushort4 v = ((const ushort4*)(B4 + off))[threadIdx.x];
        ((float4*)sx)[threadIdx.x] =
            make_float4(fmaxf(us2f(v.x), 0.f), fmaxf(us2f(v.y), 0.f),
                        fmaxf(us2f(v.z), 0.f), fmaxf(us2f(v.w), 0.f));
        __syncthreads();
        dw_comp<3, 1>(sx, w4, c, P4 + off);
        __syncthreads();
    }
    if (g5 != 0.f) {
        ushort4 v = ((const ushort4*)(B5 + off))[threadIdx.x];
        ((float4*)sx)[threadIdx.x] =
            make_float4(fmaxf(us2f(v.x), 0.f), fmaxf(us2f(v.y), 0.f),
                        fmaxf(us2f(v.z), 0.f), fmaxf(us2f(v.w), 0.f));
        __syncthreads();
        dw_comp<5, 1>(sx, w5, c, P5 + off);
    }
}

// ---------------- MFMA pw building blocks --------------------------------
// Block tile: 64 co x 64 hw x 128 ci. 256 threads = 4 waves, each wave a
// 16-co strip. Wt[co 64][ci 128+pad] bf16 (gate*BN folded); Bt[hw 64][ci
// 128+pad] bf16 (transposed In). Frags: 16B ds_read_b128.

__device__ __forceinline__ void stage_wt(unsigned short* __restrict__ Wt,
                                         const float* __restrict__ W,
                                         int co0, float s) {
    unsigned int* Wtu = (unsigned int*)Wt;
    #pragma unroll
    for (int i = 0; i < 16; ++i) {
        int idx = threadIdx.x + i * 256;   // 4096 float2 = 64x128
        int r = idx >> 6, c2 = idx & 63;
        float2 v = *(const float2*)(W + (size_t)(co0 + r) * CC + c2 * 2);
        Wtu[r * (LROW / 2) + c2] =
            (unsigned int)f2us(v.x * s) | ((unsigned int)f2us(v.y * s) << 16);
    }
}

__device__ __forceinline__ void stage_bt(unsigned short* __restrict__ Bt,
                                         const unsigned short* __restrict__ ib,
                                         int hw0) {
    #pragma unroll
    for (int i = 0; i < 16; ++i) {
        int idx = threadIdx.x + i * 256;   // 4096 uints = 128ci x 64hw
        int ci = idx >> 5, hp = (idx & 31) * 2;
        unsigned int raw = *(const unsigned int*)(ib + (size_t)ci * PLANE + hw0 + hp);
        Bt[hp * LROW + ci]       = (unsigned short)(raw & 0xffffu);
        Bt[(hp + 1) * LROW + ci] = (unsigned short)(raw >> 16);
    }
}

__device__ __forceinline__ void mfma_tile(const unsigned short* __restrict__ Wt,
                                          const unsigned short* __restrict__ Bt,
                                          int wave, int quad, int m,
                                          f32x4 acc[4]) {
    #pragma unroll
    for (int kb = 0; kb < 4; ++kb) {
        int cio = kb * 32 + quad * 8;
        bf16x8 a = *(const bf16x8*)(Wt + (wave * 16 + m) * LROW + cio);
        #pragma unroll
        for (int nt = 0; nt < 4; ++nt) {
            bf16x8 bv = *(const bf16x8*)(Bt + (nt * 16 + m) * LROW + cio);
            acc[nt] = __builtin_amdgcn_mfma_f32_16x16x32_bf16(a, bv, acc[nt], 0, 0, 0);
        }
    }
}

// ---------------------------------- mid pw (A -> B, *BN), MFMA
__global__ __launch_bounds__(256) void
k_pw_mid(const unsigned short* __restrict__ A4,
         const unsigned short* __restrict__ A5,
         const float* __restrict__ W4, const float* __restrict__ W5,
         const float* __restrict__ gates,
         unsigned short* __restrict__ B4, unsigned short* __restrict__ B5) {
    int blk = blockIdx.x;              // b*32 + coh*16 + hwt
    int hwt = blk & 15;
    int coh = (blk >> 4) & 1;
    int b = blk >> 5;
    float g4 = gates[b * 8 + 4], g5 = gates[b * 8 + 5];
    if (g4 == 0.f && g5 == 0.f) return;
    int co0 = coh * 64, hw0 = hwt * 64;
    int wave = threadIdx.x >> 6, lane = threadIdx.x & 63;
    int quad = lane >> 4, m = lane & 15;
    __shared__ unsigned short Wt[64 * LROW];
    __shared__ unsigned short Bt[64 * LROW];
    bool staged = false;
    #pragma unroll
    for (int opi = 0; opi < 2; ++opi) {
        if ((opi ? g5 : g4) == 0.f) continue;
        if (staged) __syncthreads();
        stage_wt(Wt, opi ? W5 : W4, co0, BN_SCALE);
        stage_bt(Bt, (opi ? A5 : A4) + (size_t)b * SAMP, hw0);
        __syncthreads();
        f32x4 acc[4];
        #pragma unroll
        for (int i = 0; i < 4; ++i) acc[i] = (f32x4){0.f, 0.f, 0.f, 0.f};
        mfma_tile(Wt, Bt, wave, quad, m, acc);
        unsigned short* ob = opi ? B5 : B4;
        #pragma unroll
        for (int nt = 0; nt < 4; ++nt)
            #pragma unroll
            for (int r = 0; r < 4; ++r) {
                int co = co0 + wave * 16 + quad * 4 + r;
                int col = hw0 + nt * 16 + m;
                ob[(size_t)(b * CC + co) * PLANE + col] = f2us(acc[nt][r]);
            }
        staged = true;
    }
}

// ------------- final pw: gated instances, RMW accumulate into out, MFMA
__global__ __launch_bounds__(256) void
k_pw_final(const unsigned short* __restrict__ P4,
           const unsigned short* __restrict__ P5,
           const unsigned short* __restrict__ P6,
           const unsigned short* __restrict__ P7,
           const float* __restrict__ W4, const float* __restrict__ W5,
           const float* __restrict__ W6, const float* __restrict__ W7,
           const float* __restrict__ gates,
           const int* __restrict__ cnum, const int* __restrict__ cops,
           float* __restrict__ out) {
    int blk = blockIdx.x;              // b*32 + coh*16 + hwt
    int hwt = blk & 15;
    int coh = (blk >> 4) & 1;
    int b = blk >> 5;
    int n = cnum[b];
    if (n == 0) return;                // out already holds pools/skip/zeros
    int co0 = coh * 64, hw0 = hwt * 64;
    int wave = threadIdx.x >> 6, lane = threadIdx.x & 63;
    int quad = lane >> 4, m = lane & 15;
    __shared__ unsigned short Wt[64 * LROW];
    __shared__ unsigned short Bt[64 * LROW];
    f32x4 acc[4];
    #pragma unroll
    for (int i = 0; i < 4; ++i) acc[i] = (f32x4){0.f, 0.f, 0.f, 0.f};
    for (int t = 0; t < n; ++t) {
        int op = cops[b * 4 + t];
        float gs = gates[b * 8 + op] * BN_SCALE;
        const unsigned short* src;
        const float* W;
        switch (op) {
            case 4:  src = P4; W = W4; break;
            case 5:  src = P5; W = W5; break;
            case 6:  src = P6; W = W6; break;
            default: src = P7; W = W7; break;
        }
        if (t) __syncthreads();
        stage_wt(Wt, W, co0, gs);
        stage_bt(Bt, src + (size_t)b * SAMP, hw0);
        __syncthreads();
        mfma_tile(Wt, Bt, wave, quad, m, acc);
    }
    #pragma unroll
    for (int nt = 0; nt < 4; ++nt)
        #pragma unroll
        for (int r = 0; r < 4; ++r) {
            int co = co0 + wave * 16 + quad * 4 + r;
            int col = hw0 + nt * 16 + m;
            size_t idx = (size_t)(b * CC + co) * PLANE + col;
            out[idx] += acc[nt][r];
        }
}

// ---------------------------------------------------------------- launch
extern "C" void kernel_launch(void* const* d_in, const int* in_sizes, int n_in,
                              void* d_out, int out_size, void* d_ws, size_t ws_size,
                              hipStream_t stream) {
    const float* x      = (const float*)d_in[0];
    const float* wlog   = (const float*)d_in[1];
    const float* sc3_d1 = (const float*)d_in[2];
    const float* sc3_p1 = (const float*)d_in[3];
    const float* sc3_d2 = (const float*)d_in[4];
    const float* sc3_p2 = (const float*)d_in[5];
    const float* sc5_d1 = (const float*)d_in[6];
    const float* sc5_p1 = (const float*)d_in[7];
    const float* sc5_d2 = (const float*)d_in[8];
    const float* sc5_p2 = (const float*)d_in[9];
    const float* dc3_d  = (const float*)d_in[10];
    const float* dc3_p  = (const float*)d_in[11];
    const float* dc5_d  = (const float*)d_in[12];
    const float* dc5_p  = (const float*)d_in[13];
    const void* topp    = d_in[14];

    float* out  = (float*)d_out;
    float* outw = out + NOUT0;

    float* gates = (float*)d_ws;
    int*   cnum  = (int*)((char*)d_ws + 2048);
    int*   cops  = (int*)((char*)d_ws + 2304);
    unsigned short* base = (unsigned short*)((char*)d_ws + 4096);
    unsigned short* A4 = base;
    unsigned short* A5 = base + (size_t)NOUT0;
    unsigned short* B4 = base + (size_t)NOUT0 * 2;
    unsigned short* B5 = base + (size_t)NOUT0 * 3;
    unsigned short* P4 = base + (size_t)NOUT0 * 4;
    unsigned short* P5 = base + (size_t)NOUT0 * 5;
    unsigned short* P6 = base + (size_t)NOUT0 * 6;
    unsigned short* P7 = base + (size_t)NOUT0 * 7;

    k_gates<<<1, 64, 0, stream>>>(wlog, topp, gates, cnum, cops, outw);
    k_pools<<<BB * CC, 256, 0, stream>>>(x, gates, out);
    k_dw_first<<<BB * CC, 256, 0, stream>>>(x, sc3_d1, sc5_d1, dc3_d, dc5_d,
                                            gates, A4, A5, P6, P7);
    k_pw_mid<<<BB * 32, 256, 0, stream>>>(A4, A5, sc3_p1, sc5_p1, gates, B4, B5);
    k_dw_second<<<BB * CC, 256, 0, stream>>>(B4, B5, sc3_d2, sc5_d2, gates, P4, P5);
    k_pw_final<<<BB * 32, 256, 0, stream>>>(P4, P5, P6, P7,
                                            sc3_p2, sc5_p2, dc3_p, dc5_p,
                                            gates, cnum, cops, out);
}